// Round 11
// baseline (38.269 us; speedup 1.0000x reference)
//
#include <hip/hip_runtime.h>
#include <math.h>

// Problem constants (from reference setup_inputs): B=32, N=256, D=32.
#define BB 32
#define NN 256
#define DD 32
#define TPB 256                   // 4 independent waves (no barriers!)
#define JW 32                     // j's per wave
#define NBLK (BB * 3 * 4 * 2)     // 768 = (b,type) x igroup(4) x jhalf(2)
#define NPART (NBLK * 4)          // 3072 per-wave partials
#define NORM_OFF 4096             // float offset of norms within ws
#define NORM_STRIDE 8192          // x2 at +0, y2 at +8192 (32*256 each)

__device__ __forceinline__ void pin4(float4& v) {
    asm volatile("" : "+v"(v.x), "+v"(v.y), "+v"(v.z), "+v"(v.w));
}

// |row|^2 with the EXACT 4-chain fma structure of the main kernel's dot:
// guarantees dot_ii == norm_i bitwise -> sq = fma(-2,v,v+v) = exact 0 on
// the xx/yy diagonal before the clamp.
__global__ __launch_bounds__(256) void mmd_norms(
    const float* __restrict__ x, const float* __restrict__ y,
    float* __restrict__ norms) {
    const int blk  = blockIdx.x;      // 64 = b(32) * side(2)
    const int b    = blk >> 1;
    const int side = blk & 1;
    const float* src = side ? y : x;
    const int row = threadIdx.x;
    const float4* rp = (const float4*)(src + ((size_t)b * NN + row) * DD);
    float c0 = 0.f, c1 = 0.f, c2 = 0.f, c3 = 0.f;
    #pragma unroll
    for (int k = 0; k < DD / 4; ++k) {
        float4 v = rp[k];
        c0 = fmaf(v.x, v.x, c0);
        c1 = fmaf(v.y, v.y, c1);
        c2 = fmaf(v.z, v.z, c2);
        c3 = fmaf(v.w, v.w, c3);
    }
    norms[side * NORM_STRIDE + b * NN + row] = (c0 + c1) + (c2 + c3);
}

__device__ __forceinline__ float kterm(const float4* bp, float b2,
                                       const float4* a, float a2, float negw) {
    float c0 = 0.f, c1 = 0.f, c2 = 0.f, c3 = 0.f;
    #pragma unroll
    for (int k = 0; k < DD / 4; ++k) {
        c0 = fmaf(a[k].x, bp[k].x, c0);
        c1 = fmaf(a[k].y, bp[k].y, c1);
        c2 = fmaf(a[k].z, bp[k].z, c2);
        c3 = fmaf(a[k].w, bp[k].w, c3);
    }
    const float dot = (c0 + c1) + (c2 + c3);
    float sq = fmaf(-2.0f, dot, a2 + b2);
    sq = fmaxf(sq, 1e-8f);            // folds norm clamp: sqrt(1e-8) = 1e-4
    return __expf(negw * __builtin_amdgcn_sqrtf(sq));
}

// type 0: (x,x) +1 | type 1: (y,y) +1 | type 2: (x,y) -2
// No LDS, no barriers, no atomics. Lane = one i-row (32 regs). B-rows are
// wave-uniform global loads (L1 broadcast / scalarizable), software-
// pipelined 1 deep through two STATIC buffers (p0/p1 — rule #20).
__global__ __launch_bounds__(TPB, 2) void mmd_main(
    const float* __restrict__ x, const float* __restrict__ y,
    const float* __restrict__ w, const float* __restrict__ norms,
    float* __restrict__ partials) {
    const int blk = blockIdx.x;
    const int b   = blk / 24;
    int r = blk - b * 24;
    const int type = r >> 3;
    r &= 7;
    const int ig = r >> 1;            // i-group of 64 rows
    const int jh = r & 1;             // j-half of 128 cols
    const int tid  = threadIdx.x;
    const int wave = tid >> 6;
    const int lane = tid & 63;

    const float* Abase = (type == 1) ? y : x;
    const float* Bbase = (type == 0) ? x : y;
    const float* a2v = norms + (type == 1 ? NORM_STRIDE : 0) + b * NN;
    const float* b2v = norms + (type == 0 ? 0 : NORM_STRIDE) + b * NN;

    // Per-lane i-row: 8 float4 = 32 VGPRs (R9-proven honest size).
    const int i = ig * 64 + lane;
    float4 a[DD / 4];
    {
        const float4* ar = (const float4*)(Abase + ((size_t)b * NN + i) * DD);
        #pragma unroll
        for (int k = 0; k < DD / 4; ++k) a[k] = ar[k];
    }
    #pragma unroll
    for (int k = 0; k < DD / 4; ++k) pin4(a[k]);
    float a2 = a2v[i];                // coalesced
    asm volatile("" : "+v"(a2));

    const int jbase = jh * 128 + wave * JW;
    const float4* B0 = (const float4*)(Bbase + ((size_t)b * NN + jbase) * DD);
    const float* b2p = b2v + jbase;
    const float negw = -w[b] * (1.0f / (float)DD);

    // Software pipeline: p0/p1 alternate (static indexing only).
    float4 p0[DD / 4], p1[DD / 4];
    float q0, q1;
    #pragma unroll
    for (int k = 0; k < DD / 4; ++k) p0[k] = B0[k];
    q0 = b2p[0];
    #pragma unroll
    for (int k = 0; k < DD / 4; ++k) pin4(p0[k]);

    float acc = 0.f;
    for (int j = 0; j < JW; j += 2) {
        // issue loads for j+1 into p1, then compute j from p0
        {
            const float4* Bn = B0 + (size_t)(j + 1) * (DD / 4);
            #pragma unroll
            for (int k = 0; k < DD / 4; ++k) p1[k] = Bn[k];
            q1 = b2p[j + 1];
            #pragma unroll
            for (int k = 0; k < DD / 4; ++k) pin4(p1[k]);
        }
        acc += kterm(p0, q0, a, a2, negw);
        // issue loads for j+2 into p0 (clamped on last iter), compute j+1
        {
            const int jn = (j + 2 < JW) ? j + 2 : 0;
            const float4* Bn = B0 + (size_t)jn * (DD / 4);
            #pragma unroll
            for (int k = 0; k < DD / 4; ++k) p0[k] = Bn[k];
            q0 = b2p[jn];
            #pragma unroll
            for (int k = 0; k < DD / 4; ++k) pin4(p0[k]);
        }
        acc += kterm(p1, q1, a, a2, negw);
    }

    // Deterministic wave64 reduction; one partial per wave (no barriers).
    #pragma unroll
    for (int off = 32; off > 0; off >>= 1) acc += __shfl_down(acc, off, 64);
    if (lane == 0) {
        const float weight = (type == 2) ? -2.0f : 1.0f;
        const float scale  = weight / ((float)NN * (float)NN * (float)BB);
        partials[blk * 4 + wave] = acc * scale;
    }
}

// Final deterministic reduction of NPART partials in double.
__global__ __launch_bounds__(256) void mmd_reduce(
    const float* __restrict__ partials, float* __restrict__ out) {
    double acc = 0.0;
    #pragma unroll
    for (int t = 0; t < NPART / 256; ++t)
        acc += (double)partials[threadIdx.x + t * 256];
    #pragma unroll
    for (int off = 32; off > 0; off >>= 1) acc += __shfl_down(acc, off, 64);
    __shared__ double red[4];
    if ((threadIdx.x & 63) == 0) red[threadIdx.x >> 6] = acc;
    __syncthreads();
    if (threadIdx.x == 0)
        out[0] = (float)((red[0] + red[1]) + (red[2] + red[3]));
}

extern "C" void kernel_launch(void* const* d_in, const int* in_sizes, int n_in,
                              void* d_out, int out_size, void* d_ws, size_t ws_size,
                              hipStream_t stream) {
    const float* x = (const float*)d_in[0];
    const float* y = (const float*)d_in[1];
    const float* w = (const float*)d_in[2];
    float* out = (float*)d_out;
    float* ws  = (float*)d_ws;          // [0..NPART): partials, [NORM_OFF..): norms
    float* partials = ws;
    float* norms    = ws + NORM_OFF;

    mmd_norms<<<BB * 2, 256, 0, stream>>>(x, y, norms);
    mmd_main<<<NBLK, TPB, 0, stream>>>(x, y, w, norms, partials);
    mmd_reduce<<<1, 256, 0, stream>>>(partials, out);
}

// Round 12
// 13.120 us; speedup vs baseline: 2.9168x; 2.9168x over previous
//
#include <hip/hip_runtime.h>
#include <math.h>

// Problem constants (from reference setup_inputs): B=32, N=256, D=32.
#define BB 32
#define NN 256
#define DD 32
#define TPB 256
#define NBLK (BB * 3 * 4 * 4)    // (b, type, i-quarter, j-quarter) = 1536
#define NPART NBLK

typedef short  bf16x8 __attribute__((ext_vector_type(8)));
typedef short  s16x4  __attribute__((ext_vector_type(4)));
typedef float  f32x4  __attribute__((ext_vector_type(4)));

// RNE float->bf16 (bit ops; avoids HIP bf16-API layout uncertainty).
__device__ __forceinline__ short bf16hi(float x, float& hf) {
    unsigned u = __float_as_uint(x);
    unsigned r = (u + 0x7fffu + ((u >> 16) & 1u)) >> 16;
    hf = __uint_as_float(r << 16);
    return (short)r;
}

// type 0: (x,x) +1 | type 1: (y,y) +1 | type 2: (x,y) -2
// MFMA path: dot(i,j) via bf16 hi/lo split, 3x mfma_f32_16x16x32_bf16 per
// 16x16 tile (hh + hl + lh; ll dropped ~2^-18). Diagonal of xx/yy forced
// to sq=0 (exact clamp semantics). Norms computed in-block from fp32.
__global__ __launch_bounds__(TPB) void mmd_mfma(
    const float* __restrict__ x, const float* __restrict__ y,
    const float* __restrict__ w, float* __restrict__ partials) {
    const int blk = blockIdx.x;
    const int b   = blk / 48;
    int rem = blk - b * 48;
    const int type = rem >> 4;
    rem &= 15;
    const int iq = rem >> 2;         // i-quarter (64 rows)
    const int jq = rem & 3;          // j-quarter (64 cols)
    const int tid  = threadIdx.x;
    const int wv   = tid >> 6;       // wave = one j-tile of 16
    const int lane = tid & 63;

    const float* Abase = (type == 1) ? y : x;
    const float* Bbase = (type == 0) ? x : y;
    const float* Aq = Abase + ((size_t)b * NN + iq * 64) * DD;  // 64 rows
    const float* Bq = Bbase + ((size_t)b * NN + jq * 64) * DD;  // 64 rows

    // LDS: MFMA fragments [tile(4)][lane(64)] of 8 bf16 (hi & lo), A and B,
    // plus per-row norms. Fragment layout: lane l of tile t holds
    // row/col t*16+(l&15), k = (l>>4)*8 .. +7.
    __shared__ bf16x8 Ah[4 * 64], Al[4 * 64], Bh[4 * 64], Bl[4 * 64];
    __shared__ float a2s[64], b2s[64];

    // Stage + convert: thread handles float4 #e of the contiguous 8KB
    // quarter (fully coalesced). e -> row e>>3, k-quad e&7.
    #pragma unroll
    for (int u = 0; u < 2; ++u) {
        const int e   = tid + u * 256;        // 0..511
        const int row = e >> 3;               // 0..63
        const int kq  = e & 7;                // float4 within row
        const int g   = kq >> 1;              // k-group of 8
        const int kk  = (kq & 1) * 4;         // short offset within group
        const int l   = g * 16 + (row & 15);
        const int it  = row >> 4;
        {
            float4 v = ((const float4*)Aq)[e];
            float h0, h1, h2, h3, d;
            s16x4 hi, lo;
            hi[0] = bf16hi(v.x, h0); lo[0] = bf16hi(v.x - h0, d);
            hi[1] = bf16hi(v.y, h1); lo[1] = bf16hi(v.y - h1, d);
            hi[2] = bf16hi(v.z, h2); lo[2] = bf16hi(v.z - h2, d);
            hi[3] = bf16hi(v.w, h3); lo[3] = bf16hi(v.w - h3, d);
            *(s16x4*)((short*)&Ah[it * 64 + l] + kk) = hi;
            *(s16x4*)((short*)&Al[it * 64 + l] + kk) = lo;
        }
        {
            float4 v = ((const float4*)Bq)[e];
            float h0, h1, h2, h3, d;
            s16x4 hi, lo;
            hi[0] = bf16hi(v.x, h0); lo[0] = bf16hi(v.x - h0, d);
            hi[1] = bf16hi(v.y, h1); lo[1] = bf16hi(v.y - h1, d);
            hi[2] = bf16hi(v.z, h2); lo[2] = bf16hi(v.z - h2, d);
            hi[3] = bf16hi(v.w, h3); lo[3] = bf16hi(v.w - h3, d);
            *(s16x4*)((short*)&Bh[it * 64 + l] + kk) = hi;
            *(s16x4*)((short*)&Bl[it * 64 + l] + kk) = lo;
        }
    }
    // Per-row fp32 norms (rows are L1-hot from the staging pass).
    if (tid < 128) {
        const int r = tid & 63;
        const float4* rp = (const float4*)((tid < 64 ? Aq : Bq) + (size_t)r * DD);
        float c0 = 0.f, c1 = 0.f, c2 = 0.f, c3 = 0.f;
        #pragma unroll
        for (int k = 0; k < DD / 4; ++k) {
            float4 v = rp[k];
            c0 = fmaf(v.x, v.x, c0);
            c1 = fmaf(v.y, v.y, c1);
            c2 = fmaf(v.z, v.z, c2);
            c3 = fmaf(v.w, v.w, c3);
        }
        (tid < 64 ? a2s : b2s)[r] = (c0 + c1) + (c2 + c3);
    }
    __syncthreads();

    // Compute: wave owns j-tile wv, loops 4 i-tiles.
    const bf16x8 bh = Bh[wv * 64 + lane];
    const bf16x8 bl = Bl[wv * 64 + lane];
    const float  b2 = b2s[wv * 16 + (lane & 15)];
    const float  negw = -w[b] * (1.0f / (float)DD);
    const bool   sym = (type < 2) && (iq == jq);
    const int    rowbase = (lane >> 4) * 4;
    const int    colr = lane & 15;

    float acc = 0.f;
    #pragma unroll
    for (int it = 0; it < 4; ++it) {
        const bf16x8 ah = Ah[it * 64 + lane];
        const bf16x8 al = Al[it * 64 + lane];
        f32x4 c = {0.f, 0.f, 0.f, 0.f};
        c = __builtin_amdgcn_mfma_f32_16x16x32_bf16(al, bh, c, 0, 0, 0);
        c = __builtin_amdgcn_mfma_f32_16x16x32_bf16(ah, bl, c, 0, 0, 0);
        c = __builtin_amdgcn_mfma_f32_16x16x32_bf16(ah, bh, c, 0, 0, 0);
        const f32x4 a2q = *(const f32x4*)&a2s[it * 16 + rowbase];
        const bool diagt = sym && (it == wv);
        #pragma unroll
        for (int r = 0; r < 4; ++r) {
            float sq = fmaf(-2.0f, c[r], a2q[r] + b2);
            if (diagt && (rowbase + r == colr)) sq = 0.f;
            sq = fmaxf(sq, 1e-8f);   // folds norm clamp: sqrt(1e-8) = 1e-4
            acc += __expf(negw * __builtin_amdgcn_sqrtf(sq));
        }
    }

    // Deterministic block reduction: wave shuffle + fixed-order cross-wave.
    #pragma unroll
    for (int off = 32; off > 0; off >>= 1) acc += __shfl_down(acc, off, 64);
    __shared__ float red[4];
    if (lane == 0) red[wv] = acc;
    __syncthreads();
    if (tid == 0) {
        const float bsum = (red[0] + red[1]) + (red[2] + red[3]);
        const float weight = (type == 2) ? -2.0f : 1.0f;
        const float scale  = weight / ((float)NN * (float)NN * (float)BB);
        partials[blk] = bsum * scale;
    }
}

// Final deterministic reduction of NPART partials in double.
__global__ __launch_bounds__(256) void mmd_reduce(
    const float* __restrict__ partials, float* __restrict__ out) {
    double acc = 0.0;
    #pragma unroll
    for (int t = 0; t < NPART / 256; ++t)
        acc += (double)partials[threadIdx.x + t * 256];
    #pragma unroll
    for (int off = 32; off > 0; off >>= 1) acc += __shfl_down(acc, off, 64);
    __shared__ double red[4];
    if ((threadIdx.x & 63) == 0) red[threadIdx.x >> 6] = acc;
    __syncthreads();
    if (threadIdx.x == 0)
        out[0] = (float)((red[0] + red[1]) + (red[2] + red[3]));
}

extern "C" void kernel_launch(void* const* d_in, const int* in_sizes, int n_in,
                              void* d_out, int out_size, void* d_ws, size_t ws_size,
                              hipStream_t stream) {
    const float* x = (const float*)d_in[0];
    const float* y = (const float*)d_in[1];
    const float* w = (const float*)d_in[2];
    float* out = (float*)d_out;
    float* partials = (float*)d_ws;  // NPART floats

    mmd_mfma<<<NBLK, TPB, 0, stream>>>(x, y, w, partials);
    mmd_reduce<<<1, 256, 0, stream>>>(partials, out);
}